// Round 9
// baseline (255.468 us; speedup 1.0000x reference)
//
#include <hip/hip_runtime.h>
#include <math.h>
#include <stdint.h>

#define EPS 1e-5f

typedef __attribute__((ext_vector_type(8))) short bf16x8;
typedef __attribute__((ext_vector_type(4))) float f32x4;

union FragU {
    bf16x8 v;
    ushort u[8];
};

__device__ __forceinline__ ushort f2bf(float f)
{
    union { float f; uint u; } v; v.f = f;
    uint r = v.u + 0x7FFF + ((v.u >> 16) & 1);   // RNE
    return (ushort)(r >> 16);
}
__device__ __forceinline__ float bf2f(ushort u)
{
    union { uint u; float f; } v; v.u = (uint)u << 16;
    return v.f;
}
__device__ __forceinline__ uint packbf2(float lo, float hi)
{
    return (uint)f2bf(lo) | ((uint)f2bf(hi) << 16);
}

#define MFMA(a, b, c) __builtin_amdgcn_mfma_f32_16x16x32_bf16((a), (b), (c), 0, 0, 0)

#define FP_BLOCKS 209   // fuse-pack role blocks (209*4 = 836 >= 833 units)

// ---------------------------------------------------------------------------
// Software grid barrier: grid <= 256 blocks -> all resident at launch (kernel
// is alone on the stream), so spin cannot deadlock. Bounded spin anyway:
// worst case we proceed with garbage (wrong answer), never a hang.
// ---------------------------------------------------------------------------
__device__ __forceinline__ void gbar(int* bar, int target)
{
    __syncthreads();
    if (threadIdx.x == 0) {
        __threadfence();
        __hip_atomic_fetch_add(bar, 1, __ATOMIC_ACQ_REL, __HIP_MEMORY_SCOPE_AGENT);
        long it = 0;
        while (__hip_atomic_load(bar, __ATOMIC_ACQUIRE, __HIP_MEMORY_SCOPE_AGENT)
                   < target &&
               it < (1L << 22)) {
            __builtin_amdgcn_s_sleep(2);
            ++it;
        }
    }
    __syncthreads();
}

// 256-thread block exclusive scan; also returns block total.
__device__ __forceinline__ int blockScanExcl(int v, int* wsum, int* tot)
{
    int lane = threadIdx.x & 63, wv = threadIdx.x >> 6;
    int inc = v;
#pragma unroll
    for (int off = 1; off < 64; off <<= 1) {
        int u = __shfl_up(inc, off);
        if (lane >= off) inc += u;
    }
    __syncthreads();                 // protect wsum reuse across calls
    if (lane == 63) wsum[wv] = inc;
    __syncthreads();
    int add = 0;
#pragma unroll
    for (int i = 0; i < 4; ++i)
        if (i < wv) add += wsum[i];
    *tot = wsum[0] + wsum[1] + wsum[2] + wsum[3];
    return inc + add - v;
}

// ---------------------------------------------------------------------------
// K_preh: dual-role kernel.
//  [0, NWB):            pre-MLP MFMA -> Ab (bf16, +pre_b), Bb (bf16).
//  [NWB, NWB+FP):       fuse post@lin -> Wp bf16 B-frags; bc.
//  block 0 also zeroes the csr barrier counter (stream-ordered before k_csr).
// ---------------------------------------------------------------------------
__global__ __launch_bounds__(256) void k_preh(
    const float* __restrict__ x, const float* __restrict__ pre_w,
    const float* __restrict__ pre_b,
    const float* __restrict__ post_w, const float* __restrict__ post_b,
    const float* __restrict__ lin_w, const float* __restrict__ lin_b,
    ushort* __restrict__ Ab, ushort* __restrict__ Bb,
    ushort* __restrict__ Wp, float* __restrict__ bc,
    int* __restrict__ bar, int N, int NWB)
{
    int t = threadIdx.x;
    if (blockIdx.x == 0 && t == 0) *bar = 0;

    if (blockIdx.x >= NWB) {
        // ---- fuse-pack role ----
        int unit = (blockIdx.x - NWB) * 4 + (t >> 6);
        int j = t & 63;
        if (unit > 832) return;
        if (unit < 832) {
            int r = unit;
            float acc = 0.f;
            for (int k = 0; k < 64; ++k)
                acc = fmaf(post_w[r * 64 + k], lin_w[k * 64 + j], acc);
            int tile, kk;
            if (r < 64) { tile = (r >> 5) * 4 + (j >> 4); kk = r & 31; }
            else {
                int g = (r - 64) >> 8, ka = (r - 64) & 255;
                tile = 8 + (g * 8 + (ka >> 5)) * 4 + (j >> 4); kk = ka & 31;
            }
            int ln = (j & 15) | ((kk >> 3) << 4);
            Wp[tile * 512 + ln * 8 + (kk & 7)] = f2bf(acc);
        } else {
            float a = lin_b[j];
            for (int k = 0; k < 64; ++k)
                a = fmaf(post_b[k], lin_w[k * 64 + j], a);
            bc[j] = a;
        }
        return;
    }

    // ---- pre-MLP role ----
    __shared__ ushort pw[16 * 512];
    for (int idx = t; idx < 8192; idx += 256) {
        int kin = idx >> 7, o = idx & 127;
        float v = (o < 64) ? pre_w[kin * 64 + o]
                           : pre_w[(64 + kin) * 64 + (o - 64)];
        int kk = kin & 31;
        int tile = (kin >> 5) * 8 + (o >> 4);
        int ln = (o & 15) | ((kk >> 3) << 4);
        pw[tile * 512 + ln * 8 + (kk & 7)] = f2bf(v);
    }
    __syncthreads();

    int w = t >> 6, lane = t & 63;
    int nb = (blockIdx.x * 4 + w) * 32;
    if (nb >= N) return;
    int lr = lane & 15, lk = lane >> 4;

    f32x4 acc[2][8] = {};
#pragma unroll
    for (int ks = 0; ks < 2; ++ks) {
        FragU A0, A1;
        {
            int r0 = min(nb + lr, N - 1);
            int r1 = min(nb + 16 + lr, N - 1);
            const float* p0 = &x[r0 * 64 + ks * 32 + lk * 8];
            const float* p1 = &x[r1 * 64 + ks * 32 + lk * 8];
            float4 a0 = *reinterpret_cast<const float4*>(p0);
            float4 a1 = *reinterpret_cast<const float4*>(p0 + 4);
            float4 c0 = *reinterpret_cast<const float4*>(p1);
            float4 c1 = *reinterpret_cast<const float4*>(p1 + 4);
            A0.u[0] = f2bf(a0.x); A0.u[1] = f2bf(a0.y);
            A0.u[2] = f2bf(a0.z); A0.u[3] = f2bf(a0.w);
            A0.u[4] = f2bf(a1.x); A0.u[5] = f2bf(a1.y);
            A0.u[6] = f2bf(a1.z); A0.u[7] = f2bf(a1.w);
            A1.u[0] = f2bf(c0.x); A1.u[1] = f2bf(c0.y);
            A1.u[2] = f2bf(c0.z); A1.u[3] = f2bf(c0.w);
            A1.u[4] = f2bf(c1.x); A1.u[5] = f2bf(c1.y);
            A1.u[6] = f2bf(c1.z); A1.u[7] = f2bf(c1.w);
        }
#pragma unroll
        for (int jt = 0; jt < 8; ++jt) {
            bf16x8 B = *reinterpret_cast<const bf16x8*>(
                &pw[(ks * 8 + jt) * 512 + lane * 8]);
            acc[0][jt] = MFMA(A0.v, B, acc[0][jt]);
            acc[1][jt] = MFMA(A1.v, B, acc[1][jt]);
        }
    }
#pragma unroll
    for (int mt = 0; mt < 2; ++mt)
#pragma unroll
        for (int jt = 0; jt < 8; ++jt) {
            int o = jt * 16 + lr;
#pragma unroll
            for (int rg = 0; rg < 4; ++rg) {
                int r = nb + mt * 16 + lk * 4 + rg;
                if (r < N) {
                    float v = acc[mt][jt][rg];
                    if (o < 64) Ab[r * 64 + o] = f2bf(v + pre_b[o]);
                    else        Bb[r * 64 + (o - 64)] = f2bf(v);
                }
            }
        }
}

// ---------------------------------------------------------------------------
// K_csr: full CSR build in ONE kernel, grid = NBUCK (<=256) blocks.
//   phase1 hist -> gbar -> phase2 colscan (parallel over buckets) -> gbar ->
//   phase3 bscan (block 0) -> gbar -> phase4 part -> gbar -> phase5 place.
// ---------------------------------------------------------------------------
__global__ __launch_bounds__(256) void k_csr(
    const int* __restrict__ ei, ushort* __restrict__ csr16,
    int* __restrict__ offsets, uint* __restrict__ staged,
    int* __restrict__ hist, int* __restrict__ colscan,
    int* __restrict__ bstart, float* __restrict__ avg_acc,
    int* __restrict__ bar, int E, int N)
{
    __shared__ int lh[256];
    __shared__ int wsum[4];
    __shared__ float fl[4];
    int t = threadIdx.x, bid = blockIdx.x, NB = gridDim.x;
    int chunk = (E + NB - 1) / NB;
    int c0 = bid * chunk, c1 = min(E, c0 + chunk);

    // ---- phase 1: per-chunk histogram ----
    lh[t] = 0;
    if (bid == 0 && t == 0) *avg_acc = 0.f;
    __syncthreads();
    for (int e = c0 + t; e < c1; e += 256) {
        int dst = ei[E + e];
        if ((unsigned)dst < (unsigned)N) atomicAdd(&lh[dst >> 8], 1);
    }
    __syncthreads();
    hist[bid * 256 + t] = lh[t];
    gbar(bar, 1 * NB);

    // ---- phase 2: per-bucket column scan (buckets distributed) ----
    for (int b = bid; b < 256; b += NB) {
        int v0 = (t < NB) ? hist[t * 256 + b] : 0;
        int tot;
        int excl = blockScanExcl(v0, wsum, &tot);
        if (t < NB) colscan[t * 256 + b] = excl;
        if (t == 0) bstart[b] = tot;
    }
    gbar(bar, 2 * NB);

    // ---- phase 3: scan bucket totals (block 0 only) ----
    if (bid == 0) {
        int v0 = bstart[t];
        int tot;
        int excl = blockScanExcl(v0, wsum, &tot);
        bstart[t] = excl;
        if (t == 255) {
            bstart[256] = tot;
            offsets[N] = tot;
        }
    }
    gbar(bar, 3 * NB);

    // ---- phase 4: partition own chunk into bucket-contiguous staging ----
    lh[t] = bstart[t] + colscan[bid * 256 + t];
    __syncthreads();
    for (int e = c0 + t; e < c1; e += 256) {
        int src = ei[e];
        int dst = ei[E + e];
        if ((unsigned)dst < (unsigned)N) {
            if ((unsigned)src >= (unsigned)N) src = 0;
            int pos = atomicAdd(&lh[dst >> 8], 1);
            staged[pos] = (uint)src | ((uint)(dst & 255) << 16);
        }
    }
    gbar(bar, 4 * NB);

    // ---- phase 5: place own bucket ----
    int s0 = bstart[bid], s1 = bstart[bid + 1];
    lh[t] = 0;
    __syncthreads();
    for (int i = s0 + t; i < s1; i += 256)
        atomicAdd(&lh[(staged[i] >> 16) & 255], 1);
    __syncthreads();
    int d = lh[t];
    int tot;
    int excl = blockScanExcl(d, wsum, &tot);
    int node = bid * 256 + t;
    if (node < N) offsets[node] = s0 + excl;

    float sl = (node < N) ? logf((float)d + 1.0f) : 0.f;
    for (int off = 32; off; off >>= 1) sl += __shfl_down(sl, off);
    if ((t & 63) == 0) fl[t >> 6] = sl;
    lh[t] = excl;                     // placement cursor
    __syncthreads();
    if (t == 0) atomicAdd(avg_acc, fl[0] + fl[1] + fl[2] + fl[3]);

    for (int i = s0 + t; i < s1; i += 256) {
        uint ev = staged[i];
        int p = atomicAdd(&lh[(ev >> 16) & 255], 1);
        csr16[s0 + p] = (ushort)(ev & 0xFFFFu);
    }
}

// ---------------------------------------------------------------------------
// K_aggemm: fused aggregation + output GEMM. 512 threads, 128 nodes/block.
//   Each wave: gather-aggregate its 16 nodes -> agg rows into LDS (stride 264,
//   wave-private, no barriers) -> MFMA vs pre-packed Wp -> out.
// ---------------------------------------------------------------------------
__global__ __launch_bounds__(512) void k_aggemm(
    const float* __restrict__ x, const ushort* __restrict__ Ab,
    const ushort* __restrict__ Bb, const int* __restrict__ offsets,
    const ushort* __restrict__ csr16, const float* __restrict__ avg_sum,
    const ushort* __restrict__ Wp, const float* __restrict__ bc,
    float* __restrict__ out, int N)
{
    __shared__ ushort lag[128 * 264];
    __shared__ float s_amp[128], s_att[128];

    int t = threadIdx.x, wv = t >> 6, lane = t & 63;
    int nbase = blockIdx.x * 128;
    int hl = lane & 31, which = lane >> 5;
    float avg = *avg_sum / (float)N;

    // ---- aggregate this wave's 16 nodes ----
    for (int nd = 0; nd < 16; ++nd) {
        int ln = wv * 16 + nd;
        int n = nbase + ln;
        int off0 = (n < N) ? offsets[n] : 0;
        int off1 = (n < N) ? offsets[n + 1] : 0;
        int d = off1 - off0;

        float s0 = 0.f, s1 = 0.f, q0 = 0.f, q1 = 0.f;
        float mn0 = 3.4e38f, mn1 = 3.4e38f, mx0 = -3.4e38f, mx1 = -3.4e38f;

#define UPD(bv)                                                         \
        {                                                               \
            float m0 = bf2f((ushort)((bv) & 0xFFFFu));                  \
            float m1 = bf2f((ushort)((bv) >> 16));                      \
            s0 += m0; q0 = fmaf(m0, m0, q0);                            \
            mn0 = fminf(mn0, m0); mx0 = fmaxf(mx0, m0);                 \
            s1 += m1; q1 = fmaf(m1, m1, q1);                            \
            mn1 = fminf(mn1, m1); mx1 = fmaxf(mx1, m1);                 \
        }

        for (int base = off0; base < off1; base += 64) {
            int cnt = min(64, off1 - base);
            int s_idx = 0;
            if (lane < cnt) s_idx = (int)csr16[base + lane];
            int i = 0;
            for (; i + 15 < cnt; i += 16) {
                int sA = __shfl(s_idx, i + 0 + which);
                int sB = __shfl(s_idx, i + 2 + which);
                int sC = __shfl(s_idx, i + 4 + which);
                int sD = __shfl(s_idx, i + 6 + which);
                int sE = __shfl(s_idx, i + 8 + which);
                int sF = __shfl(s_idx, i + 10 + which);
                int sG = __shfl(s_idx, i + 12 + which);
                int sH = __shfl(s_idx, i + 14 + which);
                uint bA = *reinterpret_cast<const uint*>(&Bb[(size_t)sA * 64 + hl * 2]);
                uint bB = *reinterpret_cast<const uint*>(&Bb[(size_t)sB * 64 + hl * 2]);
                uint bC = *reinterpret_cast<const uint*>(&Bb[(size_t)sC * 64 + hl * 2]);
                uint bD = *reinterpret_cast<const uint*>(&Bb[(size_t)sD * 64 + hl * 2]);
                uint bE = *reinterpret_cast<const uint*>(&Bb[(size_t)sE * 64 + hl * 2]);
                uint bF = *reinterpret_cast<const uint*>(&Bb[(size_t)sF * 64 + hl * 2]);
                uint bG = *reinterpret_cast<const uint*>(&Bb[(size_t)sG * 64 + hl * 2]);
                uint bH = *reinterpret_cast<const uint*>(&Bb[(size_t)sH * 64 + hl * 2]);
                UPD(bA); UPD(bB); UPD(bC); UPD(bD);
                UPD(bE); UPD(bF); UPD(bG); UPD(bH);
            }
            for (; i + 7 < cnt; i += 8) {
                int sA = __shfl(s_idx, i + 0 + which);
                int sB = __shfl(s_idx, i + 2 + which);
                int sC = __shfl(s_idx, i + 4 + which);
                int sD = __shfl(s_idx, i + 6 + which);
                uint bA = *reinterpret_cast<const uint*>(&Bb[(size_t)sA * 64 + hl * 2]);
                uint bB = *reinterpret_cast<const uint*>(&Bb[(size_t)sB * 64 + hl * 2]);
                uint bC = *reinterpret_cast<const uint*>(&Bb[(size_t)sC * 64 + hl * 2]);
                uint bD = *reinterpret_cast<const uint*>(&Bb[(size_t)sD * 64 + hl * 2]);
                UPD(bA); UPD(bB); UPD(bC); UPD(bD);
            }
            for (; i < cnt; i += 2) {
                int sj = __shfl(s_idx, i + which);
                uint bv = *reinterpret_cast<const uint*>(&Bb[(size_t)sj * 64 + hl * 2]);
                if ((which == 0) | (i + 1 < cnt)) UPD(bv);
            }
        }
#undef UPD

        s0 += __shfl_xor(s0, 32);  s1 += __shfl_xor(s1, 32);
        q0 += __shfl_xor(q0, 32);  q1 += __shfl_xor(q1, 32);
        mn0 = fminf(mn0, __shfl_xor(mn0, 32));
        mn1 = fminf(mn1, __shfl_xor(mn1, 32));
        mx0 = fmaxf(mx0, __shfl_xor(mx0, 32));
        mx1 = fmaxf(mx1, __shfl_xor(mx1, 32));

        uint av = *reinterpret_cast<const uint*>(
            &Ab[(size_t)min(n, N - 1) * 64 + hl * 2]);
        float a0 = bf2f((ushort)(av & 0xFFFFu));
        float a1 = bf2f((ushort)(av >> 16));

        float dc = (d > 0) ? (float)d : 1.0f;
        float mB0 = s0 / dc, mB1 = s1 / dc;
        float std0 = sqrtf(fmaxf(q0 / dc - mB0 * mB0, 0.f) + EPS);
        float std1 = sqrtf(fmaxf(q1 / dc - mB1 * mB1, 0.f) + EPS);
        float mean0 = a0 + mB0, mean1 = a1 + mB1;
        float mnF0 = a0 + mn0, mnF1 = a1 + mn1;
        float mxF0 = a0 + mx0, mxF1 = a1 + mx1;
        if (d == 0) {
            mean0 = mean1 = 0.f;
            mnF0 = mnF1 = 0.f;
            mxF0 = mxF1 = 0.f;
        }

        if (lane < 32) {
            uint* ag = reinterpret_cast<uint*>(&lag[ln * 264]);
            ag[0 * 32 + hl] = packbf2(mean0, mean1);
            ag[1 * 32 + hl] = packbf2(mnF0, mnF1);
            ag[2 * 32 + hl] = packbf2(mxF0, mxF1);
            ag[3 * 32 + hl] = packbf2(std0, std1);
        }
        if (lane == 0) {
            float dlog = logf(dc + 1.0f);
            s_amp[ln] = dlog / avg;
            s_att[ln] = avg / dlog;
        }
    }
    // no block barrier: each wave reads only its own LDS rows below.

    // ---- MFMA: rows = this wave's 16 nodes ----
    int lr = lane & 15, lk = lane >> 4;
    f32x4 accP[4] = {};
    f32x4 accA[4] = {};
    f32x4 accT[4] = {};

#pragma unroll
    for (int ks = 0; ks < 2; ++ks) {
        FragU A0;
        {
            int r0 = min(nbase + wv * 16 + lr, N - 1);
            const float* p0 = &x[r0 * 64 + ks * 32 + lk * 8];
            float4 a0 = *reinterpret_cast<const float4*>(p0);
            float4 a1 = *reinterpret_cast<const float4*>(p0 + 4);
            A0.u[0] = f2bf(a0.x); A0.u[1] = f2bf(a0.y);
            A0.u[2] = f2bf(a0.z); A0.u[3] = f2bf(a0.w);
            A0.u[4] = f2bf(a1.x); A0.u[5] = f2bf(a1.y);
            A0.u[6] = f2bf(a1.z); A0.u[7] = f2bf(a1.w);
        }
#pragma unroll
        for (int jt = 0; jt < 4; ++jt) {
            bf16x8 B = *reinterpret_cast<const bf16x8*>(
                &Wp[(ks * 4 + jt) * 512 + lane * 8]);
            accP[jt] = MFMA(A0.v, B, accP[jt]);
        }
    }

#pragma unroll 2
    for (int ks = 0; ks < 8; ++ks) {
        bf16x8 A0 = *reinterpret_cast<const bf16x8*>(
            &lag[(wv * 16 + lr) * 264 + ks * 32 + lk * 8]);
#pragma unroll
        for (int jt = 0; jt < 4; ++jt) {
            bf16x8 B0 = *reinterpret_cast<const bf16x8*>(
                &Wp[(8 + (0 * 8 + ks) * 4 + jt) * 512 + lane * 8]);
            bf16x8 B1 = *reinterpret_cast<const bf16x8*>(
                &Wp[(8 + (1 * 8 + ks) * 4 + jt) * 512 + lane * 8]);
            bf16x8 B2 = *reinterpret_cast<const bf16x8*>(
                &Wp[(8 + (2 * 8 + ks) * 4 + jt) * 512 + lane * 8]);
            accP[jt] = MFMA(A0, B0, accP[jt]);
            accA[jt] = MFMA(A0, B1, accA[jt]);
            accT[jt] = MFMA(A0, B2, accT[jt]);
        }
    }

    // ---- epilogue ----
    int rb = wv * 16 + lk * 4;
    float am[4], at[4];
#pragma unroll
    for (int rg = 0; rg < 4; ++rg) {
        am[rg] = s_amp[rb + rg];
        at[rg] = s_att[rb + rg];
    }
#pragma unroll
    for (int jt = 0; jt < 4; ++jt) {
        int j = jt * 16 + lr;
        float b = bc[j];
#pragma unroll
        for (int rg = 0; rg < 4; ++rg) {
            int r = nbase + rb + rg;
            if (r < N) {
                out[(size_t)r * 64 + j] =
                    accP[jt][rg] + am[rg] * accA[jt][rg] +
                    at[rg] * accT[jt][rg] + b;
            }
        }
    }
}

// ---------------------------------------------------------------------------
static inline char* alignup(char* p, size_t a)
{
    return (char*)(((uintptr_t)p + a - 1) & ~(uintptr_t)(a - 1));
}

extern "C" void kernel_launch(void* const* d_in, const int* in_sizes, int n_in,
                              void* d_out, int out_size, void* d_ws, size_t ws_size,
                              hipStream_t stream)
{
    const float* x      = (const float*)d_in[0];
    const int*   ei     = (const int*)d_in[1];
    const float* pre_w  = (const float*)d_in[2];
    const float* pre_b  = (const float*)d_in[3];
    const float* post_w = (const float*)d_in[4];
    const float* post_b = (const float*)d_in[5];
    const float* lin_w  = (const float*)d_in[6];
    const float* lin_b  = (const float*)d_in[7];
    float* out = (float*)d_out;

    const int N = in_sizes[0] / 64;
    const int E = in_sizes[1] / 2;
    const int Npad = (N + 127) & ~127;
    const int NWB = Npad / 128;
    const int NBUCK = (N + 255) >> 8;
    if (N > 65536) return;               // 16-bit src packing + bucket bound

    size_t need = 0;
    auto acct = [&](size_t bytes) { need = ((need + 255) & ~(size_t)255) + bytes; };
    acct((size_t)N * 64 * 2);                // Ab
    acct((size_t)N * 64 * 2);                // Bb
    acct(104 * 512 * 2);                     // Wp
    acct(64 * 4);                            // bc
    acct(((size_t)N + 1) * 4);               // offsets
    acct((size_t)E * 2);                     // csr16
    acct((size_t)E * 4);                     // staged
    acct((size_t)NBUCK * 256 * 4);           // hist
    acct((size_t)NBUCK * 256 * 4);           // colscan
    acct(257 * 4);                           // bstart
    acct(4);                                 // avg_acc
    acct(4);                                 // bar
    if (ws_size < need) return;

    char* p = (char*)d_ws;
    auto take = [&](size_t bytes) {
        p = alignup(p, 256);
        void* r = (void*)p;
        p += bytes;
        return r;
    };
    ushort* Ab      = (ushort*)take((size_t)N * 64 * 2);
    ushort* Bb      = (ushort*)take((size_t)N * 64 * 2);
    ushort* Wp      = (ushort*)take(104 * 512 * 2);
    float*  bc      = (float*)take(64 * 4);
    int*    offsets = (int*)take(((size_t)N + 1) * 4);
    ushort* csr16   = (ushort*)take((size_t)E * 2);
    uint*   staged  = (uint*)take((size_t)E * 4);
    int*    hist    = (int*)take((size_t)NBUCK * 256 * 4);
    int*    colscan = (int*)take((size_t)NBUCK * 256 * 4);
    int*    bstart  = (int*)take(257 * 4);
    float*  avg_acc = (float*)take(4);
    int*    bar     = (int*)take(4);

    k_preh<<<NWB + FP_BLOCKS, 256, 0, stream>>>(
        x, pre_w, pre_b, post_w, post_b, lin_w, lin_b,
        Ab, Bb, Wp, bc, bar, N, NWB);
    k_csr<<<NBUCK, 256, 0, stream>>>(ei, csr16, offsets, staged,
                                     hist, colscan, bstart, avg_acc, bar, E, N);
    k_aggemm<<<NWB, 512, 0, stream>>>(x, Ab, Bb, offsets, csr16, avg_acc,
                                      Wp, bc, out, N);
}

// Round 10
// 181.441 us; speedup vs baseline: 1.4080x; 1.4080x over previous
//
#include <hip/hip_runtime.h>
#include <math.h>
#include <stdint.h>

#define EPS 1e-5f

typedef __attribute__((ext_vector_type(8))) short bf16x8;
typedef __attribute__((ext_vector_type(4))) float f32x4;

union FragU {
    bf16x8 v;
    ushort u[8];
};

__device__ __forceinline__ ushort f2bf(float f)
{
    union { float f; uint u; } v; v.f = f;
    uint r = v.u + 0x7FFF + ((v.u >> 16) & 1);   // RNE
    return (ushort)(r >> 16);
}
__device__ __forceinline__ float bf2f(ushort u)
{
    union { uint u; float f; } v; v.u = (uint)u << 16;
    return v.f;
}
__device__ __forceinline__ uint packbf2(float lo, float hi)
{
    return (uint)f2bf(lo) | ((uint)f2bf(hi) << 16);
}

#define MFMA(a, b, c) __builtin_amdgcn_mfma_f32_16x16x32_bf16((a), (b), (c), 0, 0, 0)

#define PART_BLOCKS 128   // partition chunks (hist role / k_part must agree)
#define FP_BLOCKS   209   // fuse-pack role blocks (209*4 = 836 >= 833 units)

// 256-thread block exclusive scan; also returns block total.
__device__ __forceinline__ int blockScanExcl(int v, int* wsum, int* tot)
{
    int lane = threadIdx.x & 63, wv = threadIdx.x >> 6;
    int inc = v;
#pragma unroll
    for (int off = 1; off < 64; off <<= 1) {
        int u = __shfl_up(inc, off);
        if (lane >= off) inc += u;
    }
    __syncthreads();
    if (lane == 63) wsum[wv] = inc;
    __syncthreads();
    int add = 0;
#pragma unroll
    for (int i = 0; i < 4; ++i)
        if (i < wv) add += wsum[i];
    *tot = wsum[0] + wsum[1] + wsum[2] + wsum[3];
    return inc + add - v;
}

// ---------------------------------------------------------------------------
// K_preh: triple-role kernel (all roles independent).
//  [0, NWB2):                pre-MLP MFMA, 16 nodes/wave (64/block) for TLP.
//  [NWB2, NWB2+PART):        per-chunk LDS histogram of dst>>8.
//  [NWB2+PART, +FP_BLOCKS):  fuse post@lin -> Wp bf16 B-frags; bc.
// ---------------------------------------------------------------------------
__global__ __launch_bounds__(256) void k_preh(
    const float* __restrict__ x, const float* __restrict__ pre_w,
    const float* __restrict__ pre_b, const int* __restrict__ ei,
    const float* __restrict__ post_w, const float* __restrict__ post_b,
    const float* __restrict__ lin_w, const float* __restrict__ lin_b,
    ushort* __restrict__ Ab, ushort* __restrict__ Bb,
    int* __restrict__ hist, ushort* __restrict__ Wp, float* __restrict__ bc,
    int N, int E, int NWB2)
{
    int t = threadIdx.x;

    if (blockIdx.x >= NWB2 + PART_BLOCKS) {
        // ---- fuse-pack role ----
        int unit = (blockIdx.x - NWB2 - PART_BLOCKS) * 4 + (t >> 6);
        int j = t & 63;
        if (unit > 832) return;
        if (unit < 832) {
            int r = unit;
            float acc = 0.f;
            for (int k = 0; k < 64; ++k)
                acc = fmaf(post_w[r * 64 + k], lin_w[k * 64 + j], acc);
            int tile, kk;
            if (r < 64) { tile = (r >> 5) * 4 + (j >> 4); kk = r & 31; }
            else {
                int g = (r - 64) >> 8, ka = (r - 64) & 255;
                tile = 8 + (g * 8 + (ka >> 5)) * 4 + (j >> 4); kk = ka & 31;
            }
            int ln = (j & 15) | ((kk >> 3) << 4);
            Wp[tile * 512 + ln * 8 + (kk & 7)] = f2bf(acc);
        } else {
            float a = lin_b[j];
            for (int k = 0; k < 64; ++k)
                a = fmaf(post_b[k], lin_w[k * 64 + j], a);
            bc[j] = a;
        }
        return;
    }

    if (blockIdx.x >= NWB2) {
        // ---- histogram role ----
        __shared__ int lh[256];
        int blk = blockIdx.x - NWB2;
        lh[t] = 0;
        __syncthreads();
        int chunk = (E + PART_BLOCKS - 1) / PART_BLOCKS;
        int c0 = blk * chunk, c1 = min(E, c0 + chunk);
        for (int e = c0 + t; e < c1; e += 256) {
            int dst = ei[E + e];
            if ((unsigned)dst < (unsigned)N) atomicAdd(&lh[dst >> 8], 1);
        }
        __syncthreads();
        hist[blk * 256 + t] = lh[t];
        return;
    }

    // ---- pre-MLP role: 64 nodes/block, 16 nodes/wave ----
    __shared__ ushort pw[16 * 512];
    for (int idx = t; idx < 8192; idx += 256) {
        int kin = idx >> 7, o = idx & 127;
        float v = (o < 64) ? pre_w[kin * 64 + o]
                           : pre_w[(64 + kin) * 64 + (o - 64)];
        int kk = kin & 31;
        int tile = (kin >> 5) * 8 + (o >> 4);
        int ln = (o & 15) | ((kk >> 3) << 4);
        pw[tile * 512 + ln * 8 + (kk & 7)] = f2bf(v);
    }
    __syncthreads();

    int w = t >> 6, lane = t & 63;
    int nb = blockIdx.x * 64 + w * 16;
    if (nb >= N) return;
    int lr = lane & 15, lk = lane >> 4;

    f32x4 acc[8] = {};
#pragma unroll
    for (int ks = 0; ks < 2; ++ks) {
        FragU A0;
        {
            int r0 = min(nb + lr, N - 1);
            const float* p0 = &x[r0 * 64 + ks * 32 + lk * 8];
            float4 a0 = *reinterpret_cast<const float4*>(p0);
            float4 a1 = *reinterpret_cast<const float4*>(p0 + 4);
            A0.u[0] = f2bf(a0.x); A0.u[1] = f2bf(a0.y);
            A0.u[2] = f2bf(a0.z); A0.u[3] = f2bf(a0.w);
            A0.u[4] = f2bf(a1.x); A0.u[5] = f2bf(a1.y);
            A0.u[6] = f2bf(a1.z); A0.u[7] = f2bf(a1.w);
        }
#pragma unroll
        for (int jt = 0; jt < 8; ++jt) {
            bf16x8 B = *reinterpret_cast<const bf16x8*>(
                &pw[(ks * 8 + jt) * 512 + lane * 8]);
            acc[jt] = MFMA(A0.v, B, acc[jt]);
        }
    }
#pragma unroll
    for (int jt = 0; jt < 8; ++jt) {
        int o = jt * 16 + lr;
#pragma unroll
        for (int rg = 0; rg < 4; ++rg) {
            int r = nb + lk * 4 + rg;
            if (r < N) {
                float v = acc[jt][rg];
                if (o < 64) Ab[r * 64 + o] = f2bf(v + pre_b[o]);
                else        Bb[r * 64 + (o - 64)] = f2bf(v);
            }
        }
    }
}

// ---------------------------------------------------------------------------
// K_part: partition with INLINED scans (no k_cscan dispatch).
//   Each block recomputes from hist: own column prefix + bucket-start scan.
//   Block 0 publishes bstart/offsets[N]/avg_acc=0 for k_place.
// ---------------------------------------------------------------------------
__global__ __launch_bounds__(256) void k_part(
    const int* __restrict__ ei, const int* __restrict__ hist,
    int* __restrict__ bstart, uint* __restrict__ staged,
    int* __restrict__ offsets, float* __restrict__ avg_acc, int E, int N)
{
    __shared__ int cur[256];
    __shared__ int wsum[4];
    int t = threadIdx.x, blk = blockIdx.x;

    // column prefix (chunks < blk) and column total for bucket t
    int pre = 0, tot = 0;
    for (int b = 0; b < PART_BLOCKS; ++b) {
        int h = hist[b * 256 + t];
        pre += (b < blk) ? h : 0;
        tot += h;
    }
    int grand;
    int bs = blockScanExcl(tot, wsum, &grand);
    cur[t] = bs + pre;
    if (blk == 0) {
        bstart[t] = bs;
        if (t == 255) { bstart[256] = grand; offsets[N] = grand; }
        if (t == 0) *avg_acc = 0.f;
    }
    __syncthreads();

    int chunk = (E + PART_BLOCKS - 1) / PART_BLOCKS;
    int c0 = blk * chunk, c1 = min(E, c0 + chunk);
    for (int e = c0 + t; e < c1; e += 256) {
        int src = ei[e];
        int dst = ei[E + e];
        if ((unsigned)dst < (unsigned)N) {
            if ((unsigned)src >= (unsigned)N) src = 0;
            int pos = atomicAdd(&cur[dst >> 8], 1);
            staged[pos] = (uint)src | ((uint)(dst & 255) << 16);
        }
    }
}

// ---------------------------------------------------------------------------
// K_place: one block per bucket. LDS count -> LDS scan -> CSR placement
//   (ushort src) in an L2 window; offsets; log-deg sum (1 atomic/blk).
// ---------------------------------------------------------------------------
__global__ __launch_bounds__(256) void k_place(
    const uint* __restrict__ staged, const int* __restrict__ bucketStart,
    ushort* __restrict__ csr16, int* __restrict__ offsets,
    float* __restrict__ avg_acc, int N)
{
    __shared__ int cnt[256];
    __shared__ int wsum[4];
    __shared__ float fl[4];
    int t = threadIdx.x, lane = t & 63, wv = t >> 6;
    int b = blockIdx.x;
    int s0 = bucketStart[b], s1 = bucketStart[b + 1];

    cnt[t] = 0;
    __syncthreads();
    for (int i = s0 + t; i < s1; i += 256)
        atomicAdd(&cnt[(staged[i] >> 16) & 255], 1);
    __syncthreads();

    int d = cnt[t];
    int v = d;
#pragma unroll
    for (int off = 1; off < 64; off <<= 1) {
        int u = __shfl_up(v, off);
        if (lane >= off) v += u;
    }
    if (lane == 63) wsum[wv] = v;
    __syncthreads();
    int wvoff = 0;
#pragma unroll
    for (int i = 0; i < 4; ++i)
        if (i < wv) wvoff += wsum[i];
    int excl = wvoff + v - d;

    int node = b * 256 + t;
    if (node < N) offsets[node] = s0 + excl;

    float sl = (node < N) ? logf((float)d + 1.0f) : 0.f;
    for (int off = 32; off; off >>= 1) sl += __shfl_down(sl, off);
    if (lane == 0) fl[wv] = sl;

    cnt[t] = excl;            // placement cursor
    __syncthreads();
    if (t == 0) atomicAdd(avg_acc, fl[0] + fl[1] + fl[2] + fl[3]);

    for (int i = s0 + t; i < s1; i += 256) {
        uint ev = staged[i];
        int p = atomicAdd(&cnt[(ev >> 16) & 255], 1);
        csr16[s0 + p] = (ushort)(ev & 0xFFFFu);
    }
}

// ---------------------------------------------------------------------------
// K6: per-node aggregation, half-wave-per-edge, B-only statistics (round 8).
// ---------------------------------------------------------------------------
__global__ __launch_bounds__(256) void k_aggregate(
    const ushort* __restrict__ Ab, const ushort* __restrict__ Bb,
    const int* __restrict__ offsets, const ushort* __restrict__ csr16,
    const float* __restrict__ avg_sum, ushort* __restrict__ aggs,
    float* __restrict__ amp, float* __restrict__ att, int N)
{
    int wave = threadIdx.x >> 6, lane = threadIdx.x & 63;
    int n = blockIdx.x * 4 + wave;
    if (n >= N) return;

    int off0 = offsets[n], off1 = offsets[n + 1];
    int d = off1 - off0;
    int hl = lane & 31;          // feature-pair index
    int which = lane >> 5;       // 0 = even edge of pair, 1 = odd

    float s0 = 0.f, s1 = 0.f, q0 = 0.f, q1 = 0.f;
    float mn0 = 3.4e38f, mn1 = 3.4e38f, mx0 = -3.4e38f, mx1 = -3.4e38f;

#define UPD(bv)                                                         \
    {                                                                   \
        float m0 = bf2f((ushort)((bv) & 0xFFFFu));                      \
        float m1 = bf2f((ushort)((bv) >> 16));                          \
        s0 += m0; q0 = fmaf(m0, m0, q0);                                \
        mn0 = fminf(mn0, m0); mx0 = fmaxf(mx0, m0);                     \
        s1 += m1; q1 = fmaf(m1, m1, q1);                                \
        mn1 = fminf(mn1, m1); mx1 = fmaxf(mx1, m1);                     \
    }

    for (int base = off0; base < off1; base += 64) {
        int cnt = min(64, off1 - base);
        int s_idx = 0;
        if (lane < cnt) s_idx = (int)csr16[base + lane];
        int i = 0;
        for (; i + 15 < cnt; i += 16) {
            int sA = __shfl(s_idx, i + 0 + which);
            int sB = __shfl(s_idx, i + 2 + which);
            int sC = __shfl(s_idx, i + 4 + which);
            int sD = __shfl(s_idx, i + 6 + which);
            int sE = __shfl(s_idx, i + 8 + which);
            int sF = __shfl(s_idx, i + 10 + which);
            int sG = __shfl(s_idx, i + 12 + which);
            int sH = __shfl(s_idx, i + 14 + which);
            uint bA = *reinterpret_cast<const uint*>(&Bb[(size_t)sA * 64 + hl * 2]);
            uint bB = *reinterpret_cast<const uint*>(&Bb[(size_t)sB * 64 + hl * 2]);
            uint bC = *reinterpret_cast<const uint*>(&Bb[(size_t)sC * 64 + hl * 2]);
            uint bD = *reinterpret_cast<const uint*>(&Bb[(size_t)sD * 64 + hl * 2]);
            uint bE = *reinterpret_cast<const uint*>(&Bb[(size_t)sE * 64 + hl * 2]);
            uint bF = *reinterpret_cast<const uint*>(&Bb[(size_t)sF * 64 + hl * 2]);
            uint bG = *reinterpret_cast<const uint*>(&Bb[(size_t)sG * 64 + hl * 2]);
            uint bH = *reinterpret_cast<const uint*>(&Bb[(size_t)sH * 64 + hl * 2]);
            UPD(bA); UPD(bB); UPD(bC); UPD(bD);
            UPD(bE); UPD(bF); UPD(bG); UPD(bH);
        }
        for (; i + 7 < cnt; i += 8) {
            int sA = __shfl(s_idx, i + 0 + which);
            int sB = __shfl(s_idx, i + 2 + which);
            int sC = __shfl(s_idx, i + 4 + which);
            int sD = __shfl(s_idx, i + 6 + which);
            uint bA = *reinterpret_cast<const uint*>(&Bb[(size_t)sA * 64 + hl * 2]);
            uint bB = *reinterpret_cast<const uint*>(&Bb[(size_t)sB * 64 + hl * 2]);
            uint bC = *reinterpret_cast<const uint*>(&Bb[(size_t)sC * 64 + hl * 2]);
            uint bD = *reinterpret_cast<const uint*>(&Bb[(size_t)sD * 64 + hl * 2]);
            UPD(bA); UPD(bB); UPD(bC); UPD(bD);
        }
        for (; i < cnt; i += 2) {
            int sj = __shfl(s_idx, i + which);
            uint bv = *reinterpret_cast<const uint*>(&Bb[(size_t)sj * 64 + hl * 2]);
            if ((which == 0) | (i + 1 < cnt)) UPD(bv);
        }
    }
#undef UPD

    // combine half-waves
    s0 += __shfl_xor(s0, 32);  s1 += __shfl_xor(s1, 32);
    q0 += __shfl_xor(q0, 32);  q1 += __shfl_xor(q1, 32);
    mn0 = fminf(mn0, __shfl_xor(mn0, 32));
    mn1 = fminf(mn1, __shfl_xor(mn1, 32));
    mx0 = fmaxf(mx0, __shfl_xor(mx0, 32));
    mx1 = fmaxf(mx1, __shfl_xor(mx1, 32));

    uint av = *reinterpret_cast<const uint*>(&Ab[(size_t)n * 64 + hl * 2]);
    float a0 = bf2f((ushort)(av & 0xFFFFu));
    float a1 = bf2f((ushort)(av >> 16));

    float dc = (d > 0) ? (float)d : 1.0f;
    float mB0 = s0 / dc, mB1 = s1 / dc;
    float std0 = sqrtf(fmaxf(q0 / dc - mB0 * mB0, 0.f) + EPS);
    float std1 = sqrtf(fmaxf(q1 / dc - mB1 * mB1, 0.f) + EPS);
    float mean0 = a0 + mB0, mean1 = a1 + mB1;
    float mnF0 = a0 + mn0, mnF1 = a1 + mn1;
    float mxF0 = a0 + mx0, mxF1 = a1 + mx1;
    if (d == 0) {
        mean0 = mean1 = 0.f;
        mnF0 = mnF1 = 0.f;
        mxF0 = mxF1 = 0.f;
    }

    if (lane < 32) {
        uint* ag = reinterpret_cast<uint*>(&aggs[(size_t)n * 256]);
        ag[0 * 32 + hl] = packbf2(mean0, mean1);
        ag[1 * 32 + hl] = packbf2(mnF0, mnF1);
        ag[2 * 32 + hl] = packbf2(mxF0, mxF1);
        ag[3 * 32 + hl] = packbf2(std0, std1);
    }
    if (lane == 0) {
        float avg = *avg_sum / (float)N;
        float dlog = logf(dc + 1.0f);
        amp[n] = dlog / avg;
        att[n] = avg / dlog;
    }
}

// ---------------------------------------------------------------------------
// K7: output GEMM via bf16 MFMA (round 8, unchanged).
// ---------------------------------------------------------------------------
__global__ __launch_bounds__(256) void k_out_gemm(
    const float* __restrict__ x, const ushort* __restrict__ aggs,
    const float* __restrict__ amp, const float* __restrict__ att,
    const ushort* __restrict__ Wp, const float* __restrict__ bc,
    float* __restrict__ out, int N)
{
    int w = threadIdx.x >> 6, lane = threadIdx.x & 63;
    int nb = (blockIdx.x * 4 + w) * 32;
    int lr = lane & 15, lk = lane >> 4;

    f32x4 accP[2][4] = {};
    f32x4 accA[2][4] = {};
    f32x4 accT[2][4] = {};

#pragma unroll
    for (int ks = 0; ks < 2; ++ks) {
        FragU A0, A1;
        {
            int r0 = min(nb + lr, N - 1);
            int r1 = min(nb + 16 + lr, N - 1);
            const float* p0 = &x[r0 * 64 + ks * 32 + lk * 8];
            const float* p1 = &x[r1 * 64 + ks * 32 + lk * 8];
            float4 a0 = *reinterpret_cast<const float4*>(p0);
            float4 a1 = *reinterpret_cast<const float4*>(p0 + 4);
            float4 c0 = *reinterpret_cast<const float4*>(p1);
            float4 c1 = *reinterpret_cast<const float4*>(p1 + 4);
            A0.u[0] = f2bf(a0.x); A0.u[1] = f2bf(a0.y);
            A0.u[2] = f2bf(a0.z); A0.u[3] = f2bf(a0.w);
            A0.u[4] = f2bf(a1.x); A0.u[5] = f2bf(a1.y);
            A0.u[6] = f2bf(a1.z); A0.u[7] = f2bf(a1.w);
            A1.u[0] = f2bf(c0.x); A1.u[1] = f2bf(c0.y);
            A1.u[2] = f2bf(c0.z); A1.u[3] = f2bf(c0.w);
            A1.u[4] = f2bf(c1.x); A1.u[5] = f2bf(c1.y);
            A1.u[6] = f2bf(c1.z); A1.u[7] = f2bf(c1.w);
        }
#pragma unroll
        for (int jt = 0; jt < 4; ++jt) {
            bf16x8 B = *reinterpret_cast<const bf16x8*>(
                &Wp[(ks * 4 + jt) * 512 + lane * 8]);
            accP[0][jt] = MFMA(A0.v, B, accP[0][jt]);
            accP[1][jt] = MFMA(A1.v, B, accP[1][jt]);
        }
    }

#pragma unroll 2
    for (int ks = 0; ks < 8; ++ks) {
        bf16x8 A0 = *reinterpret_cast<const bf16x8*>(
            &aggs[(size_t)(nb + lr) * 256 + ks * 32 + lk * 8]);
        bf16x8 A1 = *reinterpret_cast<const bf16x8*>(
            &aggs[(size_t)(nb + 16 + lr) * 256 + ks * 32 + lk * 8]);
        bf16x8 B0[4], B1[4], B2[4];
#pragma unroll
        for (int jt = 0; jt < 4; ++jt) {
            B0[jt] = *reinterpret_cast<const bf16x8*>(
                &Wp[(8 + (0 * 8 + ks) * 4 + jt) * 512 + lane * 8]);
            B1[jt] = *reinterpret_cast<const bf16x8*>(
                &Wp[(8 + (1 * 8 + ks) * 4 + jt) * 512 + lane * 8]);
            B2[jt] = *reinterpret_cast<const bf16x8*>(
                &Wp[(8 + (2 * 8 + ks) * 4 + jt) * 512 + lane * 8]);
        }
#pragma unroll
        for (int jt = 0; jt < 4; ++jt) {
            accP[0][jt] = MFMA(A0, B0[jt], accP[0][jt]);
            accP[1][jt] = MFMA(A1, B0[jt], accP[1][jt]);
            accA[0][jt] = MFMA(A0, B1[jt], accA[0][jt]);
            accA[1][jt] = MFMA(A1, B1[jt], accA[1][jt]);
            accT[0][jt] = MFMA(A0, B2[jt], accT[0][jt]);
            accT[1][jt] = MFMA(A1, B2[jt], accT[1][jt]);
        }
    }

#pragma unroll
    for (int mt = 0; mt < 2; ++mt) {
        int rb = nb + mt * 16 + lk * 4;
        float am[4], at[4];
#pragma unroll
        for (int rg = 0; rg < 4; ++rg) {
            am[rg] = amp[rb + rg];
            at[rg] = att[rb + rg];
        }
#pragma unroll
        for (int jt = 0; jt < 4; ++jt) {
            int j = jt * 16 + lr;
            float b = bc[j];
#pragma unroll
            for (int rg = 0; rg < 4; ++rg) {
                int r = rb + rg;
                if (r < N) {
                    out[(size_t)r * 64 + j] =
                        accP[mt][jt][rg] + am[rg] * accA[mt][jt][rg] +
                        at[rg] * accT[mt][jt][rg] + b;
                }
            }
        }
    }
}

// ---------------------------------------------------------------------------
static inline char* alignup(char* p, size_t a)
{
    return (char*)(((uintptr_t)p + a - 1) & ~(uintptr_t)(a - 1));
}

extern "C" void kernel_launch(void* const* d_in, const int* in_sizes, int n_in,
                              void* d_out, int out_size, void* d_ws, size_t ws_size,
                              hipStream_t stream)
{
    const float* x      = (const float*)d_in[0];
    const int*   ei     = (const int*)d_in[1];
    const float* pre_w  = (const float*)d_in[2];
    const float* pre_b  = (const float*)d_in[3];
    const float* post_w = (const float*)d_in[4];
    const float* post_b = (const float*)d_in[5];
    const float* lin_w  = (const float*)d_in[6];
    const float* lin_b  = (const float*)d_in[7];
    float* out = (float*)d_out;

    const int N = in_sizes[0] / 64;
    const int E = in_sizes[1] / 2;
    const int Npad = (N + 127) & ~127;       // gemm/aggs padding (128)
    const int NWB  = Npad / 128;             // gemm grid
    const int NWB2 = ((N + 63) & ~63) / 64;  // pre-MLP grid (64 nodes/block)
    const int NBUCK = (N + 255) >> 8;
    if (N > 65536) return;               // 16-bit src packing + bucket bound

    size_t need = 0;
    auto acct = [&](size_t bytes) { need = ((need + 255) & ~(size_t)255) + bytes; };
    acct((size_t)N * 64 * 2);                // Ab
    acct((size_t)N * 64 * 2);                // Bb
    acct((size_t)Npad * 256 * 2);            // aggs
    acct(104 * 512 * 2);                     // Wp
    acct(64 * 4);                            // bc
    acct((size_t)Npad * 4);                  // amp
    acct((size_t)Npad * 4);                  // att
    acct(((size_t)N + 1) * 4);               // offsets
    acct((size_t)E * 2);                     // csr16
    acct((size_t)E * 4);                     // staged
    acct(PART_BLOCKS * 256 * 4);             // hist
    acct(257 * 4);                           // bstart
    acct(4);                                 // avg_acc
    if (ws_size < need) return;

    char* p = (char*)d_ws;
    auto take = [&](size_t bytes) {
        p = alignup(p, 256);
        void* r = (void*)p;
        p += bytes;
        return r;
    };
    ushort* Ab      = (ushort*)take((size_t)N * 64 * 2);
    ushort* Bb      = (ushort*)take((size_t)N * 64 * 2);
    ushort* aggs    = (ushort*)take((size_t)Npad * 256 * 2);
    ushort* Wp      = (ushort*)take(104 * 512 * 2);
    float*  bc      = (float*)take(64 * 4);
    float*  amp     = (float*)take((size_t)Npad * 4);
    float*  att     = (float*)take((size_t)Npad * 4);
    int*    offsets = (int*)take(((size_t)N + 1) * 4);
    ushort* csr16   = (ushort*)take((size_t)E * 2);
    uint*   staged  = (uint*)take((size_t)E * 4);
    int*    hist    = (int*)take(PART_BLOCKS * 256 * 4);
    int*    bstart  = (int*)take(257 * 4);
    float*  avg_acc = (float*)take(4);

    k_preh<<<NWB2 + PART_BLOCKS + FP_BLOCKS, 256, 0, stream>>>(
        x, pre_w, pre_b, ei, post_w, post_b, lin_w, lin_b,
        Ab, Bb, hist, Wp, bc, N, E, NWB2);
    k_part<<<PART_BLOCKS, 256, 0, stream>>>(ei, hist, bstart, staged,
                                            offsets, avg_acc, E, N);
    k_place<<<NBUCK, 256, 0, stream>>>(staged, bstart, csr16, offsets,
                                       avg_acc, N);
    k_aggregate<<<(N + 3) / 4, 256, 0, stream>>>(Ab, Bb, offsets, csr16,
                                                 avg_acc, aggs, amp, att, N);
    k_out_gemm<<<NWB, 256, 0, stream>>>(x, aggs, amp, att, Wp, bc, out, N);
}